// Round 17
// baseline (230.172 us; speedup 1.0000x reference)
//
#include <hip/hip_runtime.h>
#include <hip/hip_bf16.h>
#include <cstdint>
#include <cstddef>

#define GAT_H 8
#define KBMAX 256          // max buckets (N <= 65536, bucket = dst >> 8)
#define BCAP  6144         // staging region per bucket (mean fill ~4350 here)
#define SB    8            // src-octile bins per dst (src>>13, N<65536)

typedef short bf16x8 __attribute__((ext_vector_type(8)));
typedef float f32x4  __attribute__((ext_vector_type(4)));

// fp32 -> bf16 with round-to-nearest-even, as raw ushort bits
__device__ __forceinline__ unsigned bf16r(float x) {
    const unsigned u = __float_as_uint(x);
    return (u + 0x7fffu + ((u >> 16) & 1u)) >> 16;
}
#define B2F_LO(u) __uint_as_float((u) << 16)
#define B2F_HI(u) __uint_as_float((u) & 0xffff0000u)

// ======================= bucketed CSR build + W-conversion (once per call) =======================
// Blocks [0, nebB): edge scatter into per-bucket staging. Blocks [nebB, nebB+12):
// convert W2/W3 to transposed bf16 (fused to save 2 launches).

__global__ __launch_bounds__(256) void bkt_scatter(const int* __restrict__ ei,
                                                   int* __restrict__ bwoff,
                                                   unsigned* __restrict__ staging,
                                                   float* __restrict__ Mh,
                                                   const float* __restrict__ W2,
                                                   const float* __restrict__ W3,
                                                   unsigned short* __restrict__ Wt2,
                                                   unsigned short* __restrict__ Wt3,
                                                   int nE, int nN, int kb, int nebB) {
    const int tid = threadIdx.x;
    if (blockIdx.x >= nebB) {                     // ---- W-conversion tail blocks ----
        const int g0 = (blockIdx.x - nebB) * 2048 + tid;
        #pragma unroll
        for (int k = 0; k < 8; ++k) {
            const int g = g0 + k * 256;
            if (g < 128 * 64) {                   // Wt2: [128][64]
                const int c = g >> 6, kk = g & 63;
                Wt2[g] = (unsigned short)bf16r(W2[(size_t)kk * 128 + c]);
            } else if (g < 128 * 64 + 128 * 128) {  // Wt3: [128][128]
                const int g2 = g - 128 * 64;
                const int c = g2 >> 7, kk = g2 & 127;
                Wt3[g2] = (unsigned short)bf16r(W3[(size_t)kk * 128 + c]);
            }
        }
        return;
    }
    __shared__ int cnt[KBMAX];
    __shared__ int gb[KBMAX];
    if (blockIdx.x == 0 && tid < 3 * GAT_H) Mh[tid] = 0.f;
    cnt[tid] = 0;
    __syncthreads();
    const int base = blockIdx.x * 2048;
    const int ET = nE + nN;
    unsigned pk[8]; int bb[8], lr[8];
    #pragma unroll
    for (int k = 0; k < 8; ++k) {
        const int e = base + k * 256 + tid;
        bb[k] = -1;
        if (e < ET) {
            int src, dst;
            if (e < nE) { src = ei[e]; dst = ei[nE + e]; }
            else        { src = dst = e - nE; }
            pk[k] = ((unsigned)dst << 16) | (unsigned)src;
            bb[k] = dst >> 8;
            lr[k] = atomicAdd(&cnt[bb[k]], 1);
        }
    }
    __syncthreads();
    if (tid < kb)
        gb[tid] = cnt[tid] ? atomicAdd(&bwoff[tid], cnt[tid]) : 0;
    __syncthreads();
    #pragma unroll
    for (int k = 0; k < 8; ++k)
        if (bb[k] >= 0) {
            const int pos = gb[bb[k]] + lr[k];
            if (pos < BCAP)
                staging[(size_t)bb[k] * BCAP + pos] = pk[k];
        }
}

__global__ __launch_bounds__(1024) void bkt_build(const unsigned* __restrict__ staging,
                                                  const int* __restrict__ bwoff,
                                                  int* __restrict__ rowptr,
                                                  int* __restrict__ esrc, int N, int kb) {
    __shared__ int hist[256 * SB];
    __shared__ int run[256 * SB];
    __shared__ int sc[KBMAX];
    __shared__ int wt[4];
    __shared__ int wsum[16];
    __shared__ int outv[BCAP];
    const int b = blockIdx.x;
    const int tid = threadIdx.x;
    const int lane = tid & 63, wid = tid >> 6;

    if (tid < KBMAX) sc[tid] = (tid < kb) ? bwoff[tid] : 0;
    for (int i = tid; i < 256 * SB; i += 1024) { hist[i] = 0; run[i] = 0; }
    __syncthreads();

    if (tid < 256) {
        int incl = sc[tid];
        #pragma unroll
        for (int d = 1; d < 64; d <<= 1) {
            const int t2 = __shfl_up(incl, d, 64);
            if (lane >= d) incl += t2;
        }
        if (lane == 63) wt[wid] = incl;
        sc[tid] = incl;
    }
    __syncthreads();
    if (tid < 256) {
        int add = 0;
        #pragma unroll
        for (int w = 0; w < 4; ++w) if (w < wid) add += wt[w];
        sc[tid] += add;
    }
    __syncthreads();
    const int lo   = b ? sc[b - 1] : 0;
    const int cntb = sc[b] - lo;
    const int d0 = b << 8;
    const int nd = min(256, N - d0);
    const unsigned* stg = staging + (size_t)b * BCAP;
    const int lim = min(cntb, BCAP);

    for (int i = tid; i < lim; i += 1024) {
        const unsigned p = stg[i];
        const int dl = (int)(p >> 16) - d0;
        const int q  = (int)(p & 0xffffu) >> 13;
        atomicAdd(&hist[dl * SB + q], 1);
    }
    __syncthreads();

    const int b0 = hist[2 * tid], b1 = hist[2 * tid + 1];
    const int ps = b0 + b1;
    int incl = ps;
    #pragma unroll
    for (int d = 1; d < 64; d <<= 1) {
        const int t2 = __shfl_up(incl, d, 64);
        if (lane >= d) incl += t2;
    }
    if (lane == 63) wsum[wid] = incl;
    __syncthreads();
    if (tid == 0) {
        int runng = 0;
        #pragma unroll
        for (int w = 0; w < 16; ++w) { const int t2 = wsum[w]; wsum[w] = runng; runng += t2; }
    }
    __syncthreads();
    const int excl = wsum[wid] + incl - ps;
    hist[2 * tid]     = excl;
    hist[2 * tid + 1] = excl + b0;
    __syncthreads();

    if (tid < nd)
        rowptr[d0 + tid + 1] = lo + ((tid < 255) ? hist[(tid + 1) * SB] : cntb);
    if (b == 0 && tid == 0) rowptr[0] = 0;

    for (int i = tid; i < lim; i += 1024) {
        const unsigned p = stg[i];
        const int dl = (int)(p >> 16) - d0;
        const int q  = (int)(p & 0xffffu) >> 13;
        const int bin = dl * SB + q;
        const int pos = hist[bin] + atomicAdd(&run[bin], 1);
        if (pos < BCAP) outv[pos] = (int)(p & 0xffffu);
    }
    __syncthreads();
    for (int i = tid; i < lim; i += 1024) esrc[lo + i] = outv[i];
}

// ======================= MFMA node matmul + fused logits (bf16 in, bf16 out) =======================

template<int D>
__global__ __launch_bounds__(256) void matmul_mfma(
        const unsigned short* __restrict__ X,    // [N][D] bf16
        const unsigned short* __restrict__ Wt,   // [128][D] bf16
        const float* __restrict__ a_src, const float* __restrict__ a_dst,
        unsigned short* __restrict__ Hb,         // [N][128] bf16
        float* __restrict__ als, float* __restrict__ ald,
        float* __restrict__ Mh, int N) {
    constexpr int DP = D + 8;                    // staging pad
    constexpr int OP = 136;                      // output-transpose pad (128+8)
    static_assert(128 * DP >= 64 * OP, "wsh reuse too small");
    __shared__ unsigned short xs[64 * DP];
    __shared__ unsigned short wsh[128 * DP];
    __shared__ int bmax[GAT_H];
    const int tid = threadIdx.x;
    const int n0 = blockIdx.x * 64;
    if (tid < GAT_H) bmax[tid] = 0;

    for (int t = tid; t < 64 * (D / 8); t += 256) {
        const int row = t / (D / 8), c8 = (t % (D / 8)) * 8;
        const int n = n0 + row;
        uint4 u = make_uint4(0u, 0u, 0u, 0u);
        if (n < N) u = *reinterpret_cast<const uint4*>(&X[(size_t)n * D + c8]);
        *reinterpret_cast<uint4*>(&xs[row * DP + c8]) = u;
    }
    for (int t = tid; t < 128 * (D / 8); t += 256) {
        const int row = t / (D / 8), c8 = (t % (D / 8)) * 8;
        *reinterpret_cast<uint4*>(&wsh[row * DP + c8]) =
            *reinterpret_cast<const uint4*>(&Wt[(size_t)row * D + c8]);
    }
    __syncthreads();

    const int w = tid >> 6, l = tid & 63;
    const int lr = l & 15, lk = l >> 4;
    f32x4 acc[8];
    #pragma unroll
    for (int j = 0; j < 8; ++j) acc[j] = (f32x4){0.f, 0.f, 0.f, 0.f};

    #pragma unroll
    for (int ks = 0; ks < D / 32; ++ks) {
        const int kb = ks * 32 + lk * 8;
        const bf16x8 a = *reinterpret_cast<const bf16x8*>(&xs[(16 * w + lr) * DP + kb]);
        #pragma unroll
        for (int nt = 0; nt < 8; ++nt) {
            const bf16x8 bfr = *reinterpret_cast<const bf16x8*>(&wsh[(16 * nt + lr) * DP + kb]);
            acc[nt] = __builtin_amdgcn_mfma_f32_16x16x32_bf16(a, bfr, acc[nt], 0, 0, 0);
        }
    }
    __syncthreads();                              // all wsh reads complete

    // ---- fused logits via 16-lane shuffle reduce ----
    float asr[8], adr[8];
    #pragma unroll
    for (int nt = 0; nt < 8; ++nt) {
        asr[nt] = a_src[nt * 16 + lr];
        adr[nt] = a_dst[nt * 16 + lr];
    }
    float mys[4] = {0.f, 0.f, 0.f, 0.f}, myd[4] = {0.f, 0.f, 0.f, 0.f};
    #pragma unroll
    for (int r = 0; r < 4; ++r) {
        #pragma unroll
        for (int nt = 0; nt < 8; ++nt) {
            float ps = acc[nt][r] * asr[nt];
            float pd = acc[nt][r] * adr[nt];
            #pragma unroll
            for (int d = 1; d < 16; d <<= 1) {
                ps += __shfl_xor(ps, d, 16);
                pd += __shfl_xor(pd, d, 16);
            }
            if (lr == nt) { mys[r] = ps; myd[r] = pd; }
        }
    }
    #pragma unroll
    for (int r = 0; r < 4; ++r) {
        const int n = n0 + 16 * w + lk * 4 + r;
        if (lr < GAT_H && n < N) {
            als[(size_t)n * GAT_H + lr] = mys[r];
            ald[(size_t)n * GAT_H + lr] = myd[r];
            if (mys[r] > 0.f) atomicMax(&bmax[lr], __float_as_int(mys[r]));
        }
    }

    // ---- LDS transpose (reuse wsh) -> coalesced Hb writes ----
    unsigned short* trp = wsh;
    #pragma unroll
    for (int nt = 0; nt < 8; ++nt)
        #pragma unroll
        for (int r = 0; r < 4; ++r)
            trp[(16 * w + lk * 4 + r) * OP + 16 * nt + lr] = (unsigned short)bf16r(acc[nt][r]);
    __syncthreads();
    for (int t = tid; t < 64 * 16; t += 256) {
        const int row = t >> 4, c8 = (t & 15) * 8;
        const int n = n0 + row;
        if (n < N)
            *reinterpret_cast<uint4*>(&Hb[(size_t)n * 128 + c8]) =
                *reinterpret_cast<const uint4*>(&trp[row * OP + c8]);
    }
    if (tid < GAT_H) {
        const int v = bmax[tid];
        if (v > 0) atomicMax((int*)&Mh[tid], v);
    }
}

// ======================= fused VALU matmul + logits (layer 1 only: D=16) =======================

template<int D, int C, int KK, int F>
__global__ __launch_bounds__(256) void matmul_fused(
        const float* __restrict__ X, const float* __restrict__ W,
        const float* __restrict__ a_src, const float* __restrict__ a_dst,
        unsigned short* __restrict__ Hb,
        float* __restrict__ als, float* __restrict__ ald,
        float* __restrict__ Mh, int N) {
    constexpr int CG  = C / 8;
    constexpr int NGR = 256 / CG;
    constexpr int NPT = 64 / NGR;
    constexpr int XS  = KK + 4;
    __shared__ float xs[64][XS];
    __shared__ float wsh[KK][C];
    __shared__ int bmax[GAT_H];

    const int n0 = blockIdx.x * 64;
    const int tid = threadIdx.x;
    const int cg = tid % CG, ngr = tid / CG;
    const int c0 = cg * 8;
    if (tid < GAT_H) bmax[tid] = 0;

    float acc[NPT][8];
    #pragma unroll
    for (int i = 0; i < NPT; ++i)
        #pragma unroll
        for (int j = 0; j < 8; ++j) acc[i][j] = 0.f;

    for (int k0 = 0; k0 < D; k0 += KK) {
        for (int t = tid; t < 64 * (KK / 4); t += 256) {
            const int row = t / (KK / 4), c4 = (t % (KK / 4)) * 4;
            const int n = n0 + row;
            float4 v = make_float4(0.f, 0.f, 0.f, 0.f);
            if (n < N) v = *reinterpret_cast<const float4*>(&X[(size_t)n * D + k0 + c4]);
            *reinterpret_cast<float4*>(&xs[row][c4]) = v;
        }
        for (int t = tid; t < KK * (C / 4); t += 256) {
            const int row = t / (C / 4), c4 = (t % (C / 4)) * 4;
            *reinterpret_cast<float4*>(&wsh[row][c4]) =
                *reinterpret_cast<const float4*>(&W[(size_t)(k0 + row) * C + c4]);
        }
        __syncthreads();

        #pragma unroll
        for (int k4 = 0; k4 < KK; k4 += 4) {
            float4 xv[NPT];
            #pragma unroll
            for (int i = 0; i < NPT; ++i)
                xv[i] = *reinterpret_cast<const float4*>(&xs[ngr * NPT + i][k4]);
            #pragma unroll
            for (int kk = 0; kk < 4; ++kk) {
                const float4 w0 = *reinterpret_cast<const float4*>(&wsh[k4 + kk][c0]);
                const float4 w1 = *reinterpret_cast<const float4*>(&wsh[k4 + kk][c0 + 4]);
                #pragma unroll
                for (int i = 0; i < NPT; ++i) {
                    const float xk = (kk == 0) ? xv[i].x : (kk == 1) ? xv[i].y
                                   : (kk == 2) ? xv[i].z : xv[i].w;
                    acc[i][0] += xk * w0.x; acc[i][1] += xk * w0.y;
                    acc[i][2] += xk * w0.z; acc[i][3] += xk * w0.w;
                    acc[i][4] += xk * w1.x; acc[i][5] += xk * w1.y;
                    acc[i][6] += xk * w1.z; acc[i][7] += xk * w1.w;
                }
            }
        }
        __syncthreads();
    }

    const int h = c0 / F;                  // F==8: each cg owns one full head
    float asr[8], adr[8];
    #pragma unroll
    for (int q = 0; q < 8; ++q) {
        asr[q] = a_src[h * F + q];
        adr[q] = a_dst[h * F + q];
    }

    #pragma unroll
    for (int i = 0; i < NPT; ++i) {
        float s = 0.f, d2 = 0.f;
        #pragma unroll
        for (int q = 0; q < 8; ++q) { s += acc[i][q] * asr[q]; d2 += acc[i][q] * adr[q]; }
        const int n = n0 + ngr * NPT + i;
        if (n < N) {
            uint4 pk;
            pk.x = bf16r(acc[i][0]) | (bf16r(acc[i][1]) << 16);
            pk.y = bf16r(acc[i][2]) | (bf16r(acc[i][3]) << 16);
            pk.z = bf16r(acc[i][4]) | (bf16r(acc[i][5]) << 16);
            pk.w = bf16r(acc[i][6]) | (bf16r(acc[i][7]) << 16);
            *reinterpret_cast<uint4*>(&Hb[(size_t)n * C + c0]) = pk;
            als[(size_t)n * GAT_H + h] = s;
            ald[(size_t)n * GAT_H + h] = d2;
            if (s > 0.f) atomicMax(&bmax[h], __float_as_int(s));
        }
    }
    __syncthreads();
    if (tid < GAT_H) {
        const int v = bmax[tid];
        if (v > 0) atomicMax((int*)&Mh[tid], v);
    }
}

// ======================= fused gather: 2-edge unroll; bf16 output =======================

template<int F>
__global__ void gat_gather(const int* __restrict__ rowptr, const int* __restrict__ esrc,
                           const float* __restrict__ als, const float* __restrict__ ald,
                           const float* __restrict__ Mh,
                           const unsigned short* __restrict__ Hb, const float* __restrict__ b,
                           unsigned short* __restrict__ outb, int N) {
    const int t = blockIdx.x * blockDim.x + threadIdx.x;
    if (t >= N * GAT_H) return;
    const int dst = t >> 3, h = t & 7;
    const int beg = rowptr[dst], end = rowptr[dst + 1];
    const float adh = ald[t];
    float bnd = Mh[h] + adh;
    bnd = bnd > 0.f ? bnd : 0.2f * bnd;          // leaky(Mh+adh) >= segment max logit

    constexpr int NW = F / 2;                    // u32 words per head-slice
    float s = 0.f;
    float acc[F];
    #pragma unroll
    for (int j = 0; j < F; ++j) acc[j] = 0.f;

    int i = beg;
    for (; i + 1 < end; i += 2) {
        // nontemporal: esrc is a once-per-layer stream; don't evict L2-resident Hb
        const int sa = __builtin_nontemporal_load(&esrc[i]);
        const int sb = __builtin_nontemporal_load(&esrc[i + 1]);
        const float ala = als[sa * GAT_H + h];
        const float alb = als[sb * GAT_H + h];
        union { uint4 q[NW / 4]; unsigned w[NW]; } va, vb;
        const uint4* ha  = reinterpret_cast<const uint4*>(Hb + ((size_t)sa * GAT_H + h) * F);
        const uint4* hb2 = reinterpret_cast<const uint4*>(Hb + ((size_t)sb * GAT_H + h) * F);
        #pragma unroll
        for (int j = 0; j < NW / 4; ++j) { va.q[j] = ha[j]; vb.q[j] = hb2[j]; }

        float xa = ala + adh; xa = xa > 0.f ? xa : 0.2f * xa;
        float xb = alb + adh; xb = xb > 0.f ? xb : 0.2f * xb;
        const float pa = __expf(xa - bnd);
        const float pb = __expf(xb - bnd);
        s += pa + pb;
        #pragma unroll
        for (int j = 0; j < NW; ++j) {
            acc[2 * j]     += pa * B2F_LO(va.w[j]) + pb * B2F_LO(vb.w[j]);
            acc[2 * j + 1] += pa * B2F_HI(va.w[j]) + pb * B2F_HI(vb.w[j]);
        }
    }
    if (i < end) {                                // odd tail
        const int sa = __builtin_nontemporal_load(&esrc[i]);
        const float ala = als[sa * GAT_H + h];
        union { uint4 q[NW / 4]; unsigned w[NW]; } va;
        const uint4* ha = reinterpret_cast<const uint4*>(Hb + ((size_t)sa * GAT_H + h) * F);
        #pragma unroll
        for (int j = 0; j < NW / 4; ++j) va.q[j] = ha[j];
        float xa = ala + adh; xa = xa > 0.f ? xa : 0.2f * xa;
        const float pa = __expf(xa - bnd);
        s += pa;
        #pragma unroll
        for (int j = 0; j < NW; ++j) {
            acc[2 * j]     += pa * B2F_LO(va.w[j]);
            acc[2 * j + 1] += pa * B2F_HI(va.w[j]);
        }
    }

    const float inv = 1.f / s;                   // s > 0 (self-loop term)
    float val[F];
    #pragma unroll
    for (int j = 0; j < F; ++j) {
        const float v = acc[j] * inv + b[h * F + j];
        val[j] = v > 0.f ? v : expm1f(v);        // ELU
    }
    #pragma unroll
    for (int j8 = 0; j8 < F / 8; ++j8) {
        uint4 pk;
        pk.x = bf16r(val[8 * j8 + 0]) | (bf16r(val[8 * j8 + 1]) << 16);
        pk.y = bf16r(val[8 * j8 + 2]) | (bf16r(val[8 * j8 + 3]) << 16);
        pk.z = bf16r(val[8 * j8 + 4]) | (bf16r(val[8 * j8 + 5]) << 16);
        pk.w = bf16r(val[8 * j8 + 6]) | (bf16r(val[8 * j8 + 7]) << 16);
        *reinterpret_cast<uint4*>(&outb[((size_t)dst * GAT_H + h) * F + 8 * j8]) = pk;
    }
}

// ======================= pooling (bf16 in, fp32 accumulate) + MLP, fused =======================

__global__ __launch_bounds__(256) void pool_mlp_kernel(
        const unsigned short* __restrict__ Ab, const int* __restrict__ batch,
        const float* __restrict__ fc1w, const float* __restrict__ fc1b,
        const float* __restrict__ fc2w, const float* __restrict__ fc2b,
        float* __restrict__ out, int N) {
    const int g = blockIdx.x;
    int lo, hi;
    {
        int l = 0, h2 = N;
        while (l < h2) { const int mid = (l + h2) >> 1; if (batch[mid] < g) l = mid + 1; else h2 = mid; }
        lo = l;
        h2 = N;
        while (l < h2) { const int mid = (l + h2) >> 1; if (batch[mid] < g + 1) l = mid + 1; else h2 = mid; }
        hi = l;
    }
    __shared__ float part[16][128];
    __shared__ float pl[128];
    __shared__ float red2[32];
    const int tid = threadIdx.x;
    const int c8 = (tid & 15) * 8, r = tid >> 4;
    float a8[8];
    #pragma unroll
    for (int j = 0; j < 8; ++j) a8[j] = 0.f;
    for (int n = lo + r; n < hi; n += 16) {
        const uint4 u = *reinterpret_cast<const uint4*>(&Ab[(size_t)n * 128 + c8]);
        a8[0] += B2F_LO(u.x); a8[1] += B2F_HI(u.x);
        a8[2] += B2F_LO(u.y); a8[3] += B2F_HI(u.y);
        a8[4] += B2F_LO(u.z); a8[5] += B2F_HI(u.z);
        a8[6] += B2F_LO(u.w); a8[7] += B2F_HI(u.w);
    }
    #pragma unroll
    for (int j = 0; j < 8; ++j) part[r][c8 + j] = a8[j];
    __syncthreads();
    if (tid < 128) {
        float s = 0.f;
        #pragma unroll
        for (int rr = 0; rr < 16; ++rr) s += part[rr][tid];
        pl[tid] = s / fmaxf((float)(hi - lo), 1.f);
    }
    __syncthreads();
    if (tid < 32) {
        float a = fc1b[tid];
        for (int k = 0; k < 128; ++k) a += pl[k] * fc1w[k * 32 + tid];
        a = fmaxf(a, 0.f);
        red2[tid] = a * fc2w[tid];
    }
    __syncthreads();
    if (tid == 0) {
        float sum = fc2b[0];
        for (int k = 0; k < 32; ++k) sum += red2[k];
        out[g] = sum;
    }
}

// ======================= launch =======================

extern "C" void kernel_launch(void* const* d_in, const int* in_sizes, int n_in,
                              void* d_out, int out_size, void* d_ws, size_t ws_size,
                              hipStream_t stream) {
    const float* x     = (const float*)d_in[0];
    const int*   ei    = (const int*)  d_in[1];
    const int*   batch = (const int*)  d_in[2];
    const float* W1 = (const float*)d_in[3],  *as1 = (const float*)d_in[4],
               *ad1 = (const float*)d_in[5],  *b1  = (const float*)d_in[6];
    const float* W2 = (const float*)d_in[7],  *as2 = (const float*)d_in[8],
               *ad2 = (const float*)d_in[9],  *b2  = (const float*)d_in[10];
    const float* W3 = (const float*)d_in[11], *as3 = (const float*)d_in[12],
               *ad3 = (const float*)d_in[13], *b3  = (const float*)d_in[14];
    const float* fc1w = (const float*)d_in[15], *fc1b = (const float*)d_in[16];
    const float* fc2w = (const float*)d_in[17], *fc2b = (const float*)d_in[18];

    const int N  = in_sizes[0] / 16;     // 50000
    const int NE = in_sizes[1] / 2;      // 800000
    const int NG = out_size;             // 256
    const int ET = NE + N;               // edges incl. self-loops
    const int KB = (N + 255) >> 8;       // buckets of 256 dsts

    // workspace layout (16B alignment maintained)
    float* ws = (float*)d_ws;
    size_t off = 0;
    unsigned short* Ab = (unsigned short*)(ws + off); off += (size_t)N * 64;   // layer out (bf16)
    unsigned short* Hb = (unsigned short*)(ws + off); off += (size_t)N * 64;   // bf16 h
    float* als  = ws + off; off += (size_t)N * GAT_H;
    float* ald  = ws + off; off += (size_t)N * GAT_H;
    float* Mh   = ws + off; off += 3 * GAT_H;
    int* rowptr = (int*)(ws + off); off += N + 1;
    int* esrc   = (int*)(ws + off); off += ET;
    unsigned* staging = (unsigned*)(ws + off); off += (size_t)KB * BCAP;
    int* bwoff  = (int*)(ws + off); off += KBMAX;
    unsigned short* Wt2 = (unsigned short*)(ws + off); off += 128 * 64 / 2;    // [128][64] bf16
    unsigned short* Wt3 = (unsigned short*)(ws + off); off += 128 * 128 / 2;   // [128][128] bf16

    // ---- bucketed CSR build (+ fused W transposes in tail blocks) ----
    const int NEB = (ET + 2047) / 2048;                    // edge-scatter blocks
    const int WCB = (128 * 64 + 128 * 128 + 2047) / 2048;  // w-conv blocks (12)
    hipMemsetAsync(bwoff, 0, KBMAX * sizeof(int), stream);
    bkt_scatter<<<NEB + WCB, 256, 0, stream>>>(ei, bwoff, staging, Mh,
                                               W2, W3, Wt2, Wt3, NE, N, KB, NEB);
    bkt_build<<<KB, 1024, 0, stream>>>(staging, bwoff, rowptr, esrc, N, KB);

    const int NH = N * GAT_H;
    const int NHB = (NH + 255) / 256;
    const int NB = (N + 63) / 64;

    // ---- layer 1: 16 -> 8x8 (fp32 in, VALU fused) ----
    matmul_fused<16, 64, 16, 8><<<NB, 256, 0, stream>>>(x, W1, as1, ad1, Hb, als, ald, Mh, N);
    gat_gather<8><<<NHB, 256, 0, stream>>>(rowptr, esrc, als, ald, Mh, Hb, b1, Ab, N);

    // ---- layer 2: 64 -> 8x16 (MFMA, fused logits) ----
    matmul_mfma<64><<<NB, 256, 0, stream>>>(Ab, Wt2, as2, ad2, Hb, als, ald, Mh + GAT_H, N);
    gat_gather<16><<<NHB, 256, 0, stream>>>(rowptr, esrc, als, ald, Mh + GAT_H, Hb, b2, Ab, N);

    // ---- layer 3: 128 -> 8x16 (MFMA, fused logits) ----
    matmul_mfma<128><<<NB, 256, 0, stream>>>(Ab, Wt3, as3, ad3, Hb, als, ald, Mh + 2 * GAT_H, N);
    gat_gather<16><<<NHB, 256, 0, stream>>>(rowptr, esrc, als, ald, Mh + 2 * GAT_H, Hb, b3, Ab, N);

    // ---- pool + MLP ----
    pool_mlp_kernel<<<NG, 256, 0, stream>>>(Ab, batch, fc1w, fc1b, fc2w, fc2b,
                                            (float*)d_out, N);
}

// Round 18
// 218.172 us; speedup vs baseline: 1.0550x; 1.0550x over previous
//
#include <hip/hip_runtime.h>
#include <hip/hip_bf16.h>
#include <cstdint>
#include <cstddef>

#define GAT_H 8
#define KBMAX 256          // max buckets (N <= 65536, bucket = dst >> 8)
#define BCAP  6144         // staging region per bucket (mean fill ~4350 here)
#define SB    8            // src-octile bins per dst (src>>13, N<65536)

typedef short bf16x8 __attribute__((ext_vector_type(8)));
typedef float f32x4  __attribute__((ext_vector_type(4)));

// fp32 -> bf16 with round-to-nearest-even, as raw ushort bits
__device__ __forceinline__ unsigned bf16r(float x) {
    const unsigned u = __float_as_uint(x);
    return (u + 0x7fffu + ((u >> 16) & 1u)) >> 16;
}
#define B2F_LO(u) __uint_as_float((u) << 16)
#define B2F_HI(u) __uint_as_float((u) & 0xffff0000u)

// ======================= bucketed CSR build (once per call) =======================

__global__ __launch_bounds__(256) void bkt_scatter(const int* __restrict__ ei,
                                                   int* __restrict__ bwoff,
                                                   unsigned* __restrict__ staging,
                                                   float* __restrict__ Mh,
                                                   int nE, int nN, int kb) {
    __shared__ int cnt[KBMAX];
    __shared__ int gb[KBMAX];
    const int tid = threadIdx.x;
    if (blockIdx.x == 0 && tid < 3 * GAT_H) Mh[tid] = 0.f;
    cnt[tid] = 0;
    __syncthreads();
    const int base = blockIdx.x * 2048;
    const int ET = nE + nN;
    unsigned pk[8]; int bb[8], lr[8];
    #pragma unroll
    for (int k = 0; k < 8; ++k) {
        const int e = base + k * 256 + tid;
        bb[k] = -1;
        if (e < ET) {
            int src, dst;
            if (e < nE) { src = ei[e]; dst = ei[nE + e]; }
            else        { src = dst = e - nE; }
            pk[k] = ((unsigned)dst << 16) | (unsigned)src;
            bb[k] = dst >> 8;
            lr[k] = atomicAdd(&cnt[bb[k]], 1);
        }
    }
    __syncthreads();
    if (tid < kb)
        gb[tid] = cnt[tid] ? atomicAdd(&bwoff[tid], cnt[tid]) : 0;
    __syncthreads();
    #pragma unroll
    for (int k = 0; k < 8; ++k)
        if (bb[k] >= 0) {
            const int pos = gb[bb[k]] + lr[k];
            if (pos < BCAP)
                staging[(size_t)bb[k] * BCAP + pos] = pk[k];
        }
}

__global__ __launch_bounds__(1024) void bkt_build(const unsigned* __restrict__ staging,
                                                  const int* __restrict__ bwoff,
                                                  int* __restrict__ rowptr,
                                                  int* __restrict__ esrc, int N, int kb) {
    __shared__ int hist[256 * SB];
    __shared__ int run[256 * SB];
    __shared__ int sc[KBMAX];
    __shared__ int wt[4];
    __shared__ int wsum[16];
    __shared__ int outv[BCAP];
    const int b = blockIdx.x;
    const int tid = threadIdx.x;
    const int lane = tid & 63, wid = tid >> 6;

    if (tid < KBMAX) sc[tid] = (tid < kb) ? bwoff[tid] : 0;
    for (int i = tid; i < 256 * SB; i += 1024) { hist[i] = 0; run[i] = 0; }
    __syncthreads();

    if (tid < 256) {
        int incl = sc[tid];
        #pragma unroll
        for (int d = 1; d < 64; d <<= 1) {
            const int t2 = __shfl_up(incl, d, 64);
            if (lane >= d) incl += t2;
        }
        if (lane == 63) wt[wid] = incl;
        sc[tid] = incl;
    }
    __syncthreads();
    if (tid < 256) {
        int add = 0;
        #pragma unroll
        for (int w = 0; w < 4; ++w) if (w < wid) add += wt[w];
        sc[tid] += add;
    }
    __syncthreads();
    const int lo   = b ? sc[b - 1] : 0;
    const int cntb = sc[b] - lo;
    const int d0 = b << 8;
    const int nd = min(256, N - d0);
    const unsigned* stg = staging + (size_t)b * BCAP;
    const int lim = min(cntb, BCAP);

    for (int i = tid; i < lim; i += 1024) {
        const unsigned p = stg[i];
        const int dl = (int)(p >> 16) - d0;
        const int q  = (int)(p & 0xffffu) >> 13;
        atomicAdd(&hist[dl * SB + q], 1);
    }
    __syncthreads();

    const int b0 = hist[2 * tid], b1 = hist[2 * tid + 1];
    const int ps = b0 + b1;
    int incl = ps;
    #pragma unroll
    for (int d = 1; d < 64; d <<= 1) {
        const int t2 = __shfl_up(incl, d, 64);
        if (lane >= d) incl += t2;
    }
    if (lane == 63) wsum[wid] = incl;
    __syncthreads();
    if (tid == 0) {
        int runng = 0;
        #pragma unroll
        for (int w = 0; w < 16; ++w) { const int t2 = wsum[w]; wsum[w] = runng; runng += t2; }
    }
    __syncthreads();
    const int excl = wsum[wid] + incl - ps;
    hist[2 * tid]     = excl;
    hist[2 * tid + 1] = excl + b0;
    __syncthreads();

    if (tid < nd)
        rowptr[d0 + tid + 1] = lo + ((tid < 255) ? hist[(tid + 1) * SB] : cntb);
    if (b == 0 && tid == 0) rowptr[0] = 0;

    for (int i = tid; i < lim; i += 1024) {
        const unsigned p = stg[i];
        const int dl = (int)(p >> 16) - d0;
        const int q  = (int)(p & 0xffffu) >> 13;
        const int bin = dl * SB + q;
        const int pos = hist[bin] + atomicAdd(&run[bin], 1);
        if (pos < BCAP) outv[pos] = (int)(p & 0xffffu);
    }
    __syncthreads();
    for (int i = tid; i < lim; i += 1024) esrc[lo + i] = outv[i];
}

// ======================= W transpose+bf16 (once per call, per heavy layer) =======================

__global__ void wconv_kernel(const float* __restrict__ W, unsigned short* __restrict__ Wt, int D) {
    const int t = blockIdx.x * blockDim.x + threadIdx.x;
    if (t >= 128 * D) return;
    const int c = t / D, k = t % D;
    Wt[t] = (unsigned short)bf16r(W[(size_t)k * 128 + c]);
}

// ======================= MFMA node matmul + fused logits (bf16 in, bf16 out) =======================
// 64-node x 128-col tile per 256-thread block. A: row=l&15, k=8*(l>>4)+e;
// B: col=l&15; C/D: col=lane&15, row=(lane>>4)*4+reg (verified r15, absmax unchanged).

template<int D>
__global__ __launch_bounds__(256) void matmul_mfma(
        const unsigned short* __restrict__ X,    // [N][D] bf16
        const unsigned short* __restrict__ Wt,   // [128][D] bf16
        const float* __restrict__ a_src, const float* __restrict__ a_dst,
        unsigned short* __restrict__ Hb,         // [N][128] bf16
        float* __restrict__ als, float* __restrict__ ald,
        float* __restrict__ Mh, int N) {
    constexpr int DP = D + 8;                    // staging pad
    constexpr int OP = 136;                      // output-transpose pad (128+8)
    static_assert(128 * DP >= 64 * OP, "wsh reuse too small");
    __shared__ unsigned short xs[64 * DP];
    __shared__ unsigned short wsh[128 * DP];
    __shared__ int bmax[GAT_H];
    const int tid = threadIdx.x;
    const int n0 = blockIdx.x * 64;
    if (tid < GAT_H) bmax[tid] = 0;

    for (int t = tid; t < 64 * (D / 8); t += 256) {
        const int row = t / (D / 8), c8 = (t % (D / 8)) * 8;
        const int n = n0 + row;
        uint4 u = make_uint4(0u, 0u, 0u, 0u);
        if (n < N) u = *reinterpret_cast<const uint4*>(&X[(size_t)n * D + c8]);
        *reinterpret_cast<uint4*>(&xs[row * DP + c8]) = u;
    }
    for (int t = tid; t < 128 * (D / 8); t += 256) {
        const int row = t / (D / 8), c8 = (t % (D / 8)) * 8;
        *reinterpret_cast<uint4*>(&wsh[row * DP + c8]) =
            *reinterpret_cast<const uint4*>(&Wt[(size_t)row * D + c8]);
    }
    __syncthreads();

    const int w = tid >> 6, l = tid & 63;
    const int lr = l & 15, lk = l >> 4;
    f32x4 acc[8];
    #pragma unroll
    for (int j = 0; j < 8; ++j) acc[j] = (f32x4){0.f, 0.f, 0.f, 0.f};

    #pragma unroll
    for (int ks = 0; ks < D / 32; ++ks) {
        const int kb = ks * 32 + lk * 8;
        const bf16x8 a = *reinterpret_cast<const bf16x8*>(&xs[(16 * w + lr) * DP + kb]);
        #pragma unroll
        for (int nt = 0; nt < 8; ++nt) {
            const bf16x8 bfr = *reinterpret_cast<const bf16x8*>(&wsh[(16 * nt + lr) * DP + kb]);
            acc[nt] = __builtin_amdgcn_mfma_f32_16x16x32_bf16(a, bfr, acc[nt], 0, 0, 0);
        }
    }
    __syncthreads();                              // all wsh reads complete

    // ---- fused logits via 16-lane shuffle reduce ----
    float asr[8], adr[8];
    #pragma unroll
    for (int nt = 0; nt < 8; ++nt) {
        asr[nt] = a_src[nt * 16 + lr];
        adr[nt] = a_dst[nt * 16 + lr];
    }
    float mys[4] = {0.f, 0.f, 0.f, 0.f}, myd[4] = {0.f, 0.f, 0.f, 0.f};
    #pragma unroll
    for (int r = 0; r < 4; ++r) {
        #pragma unroll
        for (int nt = 0; nt < 8; ++nt) {
            float ps = acc[nt][r] * asr[nt];
            float pd = acc[nt][r] * adr[nt];
            #pragma unroll
            for (int d = 1; d < 16; d <<= 1) {
                ps += __shfl_xor(ps, d, 16);
                pd += __shfl_xor(pd, d, 16);
            }
            if (lr == nt) { mys[r] = ps; myd[r] = pd; }
        }
    }
    #pragma unroll
    for (int r = 0; r < 4; ++r) {
        const int n = n0 + 16 * w + lk * 4 + r;
        if (lr < GAT_H && n < N) {
            als[(size_t)n * GAT_H + lr] = mys[r];
            ald[(size_t)n * GAT_H + lr] = myd[r];
            if (mys[r] > 0.f) atomicMax(&bmax[lr], __float_as_int(mys[r]));
        }
    }

    // ---- LDS transpose (reuse wsh) -> coalesced Hb writes ----
    unsigned short* trp = wsh;
    #pragma unroll
    for (int nt = 0; nt < 8; ++nt)
        #pragma unroll
        for (int r = 0; r < 4; ++r)
            trp[(16 * w + lk * 4 + r) * OP + 16 * nt + lr] = (unsigned short)bf16r(acc[nt][r]);
    __syncthreads();
    for (int t = tid; t < 64 * 16; t += 256) {
        const int row = t >> 4, c8 = (t & 15) * 8;
        const int n = n0 + row;
        if (n < N)
            *reinterpret_cast<uint4*>(&Hb[(size_t)n * 128 + c8]) =
                *reinterpret_cast<const uint4*>(&trp[row * OP + c8]);
    }
    if (tid < GAT_H) {
        const int v = bmax[tid];
        if (v > 0) atomicMax((int*)&Mh[tid], v);
    }
}

// ======================= fused VALU matmul + logits (layer 1 only: D=16) =======================

template<int D, int C, int KK, int F>
__global__ __launch_bounds__(256) void matmul_fused(
        const float* __restrict__ X, const float* __restrict__ W,
        const float* __restrict__ a_src, const float* __restrict__ a_dst,
        unsigned short* __restrict__ Hb,
        float* __restrict__ als, float* __restrict__ ald,
        float* __restrict__ Mh, int N) {
    constexpr int CG  = C / 8;
    constexpr int NGR = 256 / CG;
    constexpr int NPT = 64 / NGR;
    constexpr int XS  = KK + 4;
    __shared__ float xs[64][XS];
    __shared__ float wsh[KK][C];
    __shared__ int bmax[GAT_H];

    const int n0 = blockIdx.x * 64;
    const int tid = threadIdx.x;
    const int cg = tid % CG, ngr = tid / CG;
    const int c0 = cg * 8;
    if (tid < GAT_H) bmax[tid] = 0;

    float acc[NPT][8];
    #pragma unroll
    for (int i = 0; i < NPT; ++i)
        #pragma unroll
        for (int j = 0; j < 8; ++j) acc[i][j] = 0.f;

    for (int k0 = 0; k0 < D; k0 += KK) {
        for (int t = tid; t < 64 * (KK / 4); t += 256) {
            const int row = t / (KK / 4), c4 = (t % (KK / 4)) * 4;
            const int n = n0 + row;
            float4 v = make_float4(0.f, 0.f, 0.f, 0.f);
            if (n < N) v = *reinterpret_cast<const float4*>(&X[(size_t)n * D + k0 + c4]);
            *reinterpret_cast<float4*>(&xs[row][c4]) = v;
        }
        for (int t = tid; t < KK * (C / 4); t += 256) {
            const int row = t / (C / 4), c4 = (t % (C / 4)) * 4;
            *reinterpret_cast<float4*>(&wsh[row][c4]) =
                *reinterpret_cast<const float4*>(&W[(size_t)(k0 + row) * C + c4]);
        }
        __syncthreads();

        #pragma unroll
        for (int k4 = 0; k4 < KK; k4 += 4) {
            float4 xv[NPT];
            #pragma unroll
            for (int i = 0; i < NPT; ++i)
                xv[i] = *reinterpret_cast<const float4*>(&xs[ngr * NPT + i][k4]);
            #pragma unroll
            for (int kk = 0; kk < 4; ++kk) {
                const float4 w0 = *reinterpret_cast<const float4*>(&wsh[k4 + kk][c0]);
                const float4 w1 = *reinterpret_cast<const float4*>(&wsh[k4 + kk][c0 + 4]);
                #pragma unroll
                for (int i = 0; i < NPT; ++i) {
                    const float xk = (kk == 0) ? xv[i].x : (kk == 1) ? xv[i].y
                                   : (kk == 2) ? xv[i].z : xv[i].w;
                    acc[i][0] += xk * w0.x; acc[i][1] += xk * w0.y;
                    acc[i][2] += xk * w0.z; acc[i][3] += xk * w0.w;
                    acc[i][4] += xk * w1.x; acc[i][5] += xk * w1.y;
                    acc[i][6] += xk * w1.z; acc[i][7] += xk * w1.w;
                }
            }
        }
        __syncthreads();
    }

    const int h = c0 / F;                  // F==8: each cg owns one full head
    float asr[8], adr[8];
    #pragma unroll
    for (int q = 0; q < 8; ++q) {
        asr[q] = a_src[h * F + q];
        adr[q] = a_dst[h * F + q];
    }

    #pragma unroll
    for (int i = 0; i < NPT; ++i) {
        float s = 0.f, d2 = 0.f;
        #pragma unroll
        for (int q = 0; q < 8; ++q) { s += acc[i][q] * asr[q]; d2 += acc[i][q] * adr[q]; }
        const int n = n0 + ngr * NPT + i;
        if (n < N) {
            uint4 pk;
            pk.x = bf16r(acc[i][0]) | (bf16r(acc[i][1]) << 16);
            pk.y = bf16r(acc[i][2]) | (bf16r(acc[i][3]) << 16);
            pk.z = bf16r(acc[i][4]) | (bf16r(acc[i][5]) << 16);
            pk.w = bf16r(acc[i][6]) | (bf16r(acc[i][7]) << 16);
            *reinterpret_cast<uint4*>(&Hb[(size_t)n * C + c0]) = pk;
            als[(size_t)n * GAT_H + h] = s;
            ald[(size_t)n * GAT_H + h] = d2;
            if (s > 0.f) atomicMax(&bmax[h], __float_as_int(s));
        }
    }
    __syncthreads();
    if (tid < GAT_H) {
        const int v = bmax[tid];
        if (v > 0) atomicMax((int*)&Mh[tid], v);
    }
}

// ======================= fused gather: 2-edge unroll; bf16 output =======================

template<int F>
__global__ void gat_gather(const int* __restrict__ rowptr, const int* __restrict__ esrc,
                           const float* __restrict__ als, const float* __restrict__ ald,
                           const float* __restrict__ Mh,
                           const unsigned short* __restrict__ Hb, const float* __restrict__ b,
                           unsigned short* __restrict__ outb, int N) {
    const int t = blockIdx.x * blockDim.x + threadIdx.x;
    if (t >= N * GAT_H) return;
    const int dst = t >> 3, h = t & 7;
    const int beg = rowptr[dst], end = rowptr[dst + 1];
    const float adh = ald[t];
    float bnd = Mh[h] + adh;
    bnd = bnd > 0.f ? bnd : 0.2f * bnd;          // leaky(Mh+adh) >= segment max logit

    constexpr int NW = F / 2;                    // u32 words per head-slice
    float s = 0.f;
    float acc[F];
    #pragma unroll
    for (int j = 0; j < F; ++j) acc[j] = 0.f;

    int i = beg;
    for (; i + 1 < end; i += 2) {
        const int sa = esrc[i], sb = esrc[i + 1];
        const float ala = als[sa * GAT_H + h];
        const float alb = als[sb * GAT_H + h];
        union { uint4 q[NW / 4]; unsigned w[NW]; } va, vb;
        const uint4* ha  = reinterpret_cast<const uint4*>(Hb + ((size_t)sa * GAT_H + h) * F);
        const uint4* hb2 = reinterpret_cast<const uint4*>(Hb + ((size_t)sb * GAT_H + h) * F);
        #pragma unroll
        for (int j = 0; j < NW / 4; ++j) { va.q[j] = ha[j]; vb.q[j] = hb2[j]; }

        float xa = ala + adh; xa = xa > 0.f ? xa : 0.2f * xa;
        float xb = alb + adh; xb = xb > 0.f ? xb : 0.2f * xb;
        const float pa = __expf(xa - bnd);
        const float pb = __expf(xb - bnd);
        s += pa + pb;
        #pragma unroll
        for (int j = 0; j < NW; ++j) {
            acc[2 * j]     += pa * B2F_LO(va.w[j]) + pb * B2F_LO(vb.w[j]);
            acc[2 * j + 1] += pa * B2F_HI(va.w[j]) + pb * B2F_HI(vb.w[j]);
        }
    }
    if (i < end) {                                // odd tail
        const int sa = esrc[i];
        const float ala = als[sa * GAT_H + h];
        union { uint4 q[NW / 4]; unsigned w[NW]; } va;
        const uint4* ha = reinterpret_cast<const uint4*>(Hb + ((size_t)sa * GAT_H + h) * F);
        #pragma unroll
        for (int j = 0; j < NW / 4; ++j) va.q[j] = ha[j];
        float xa = ala + adh; xa = xa > 0.f ? xa : 0.2f * xa;
        const float pa = __expf(xa - bnd);
        s += pa;
        #pragma unroll
        for (int j = 0; j < NW; ++j) {
            acc[2 * j]     += pa * B2F_LO(va.w[j]);
            acc[2 * j + 1] += pa * B2F_HI(va.w[j]);
        }
    }

    const float inv = 1.f / s;                   // s > 0 (self-loop term)
    float val[F];
    #pragma unroll
    for (int j = 0; j < F; ++j) {
        const float v = acc[j] * inv + b[h * F + j];
        val[j] = v > 0.f ? v : expm1f(v);        // ELU
    }
    #pragma unroll
    for (int j8 = 0; j8 < F / 8; ++j8) {
        uint4 pk;
        pk.x = bf16r(val[8 * j8 + 0]) | (bf16r(val[8 * j8 + 1]) << 16);
        pk.y = bf16r(val[8 * j8 + 2]) | (bf16r(val[8 * j8 + 3]) << 16);
        pk.z = bf16r(val[8 * j8 + 4]) | (bf16r(val[8 * j8 + 5]) << 16);
        pk.w = bf16r(val[8 * j8 + 6]) | (bf16r(val[8 * j8 + 7]) << 16);
        *reinterpret_cast<uint4*>(&outb[((size_t)dst * GAT_H + h) * F + 8 * j8]) = pk;
    }
}

// ======================= pooling (bf16 in, fp32 accumulate) + MLP, fused =======================

__global__ __launch_bounds__(256) void pool_mlp_kernel(
        const unsigned short* __restrict__ Ab, const int* __restrict__ batch,
        const float* __restrict__ fc1w, const float* __restrict__ fc1b,
        const float* __restrict__ fc2w, const float* __restrict__ fc2b,
        float* __restrict__ out, int N) {
    const int g = blockIdx.x;
    int lo, hi;
    {
        int l = 0, h2 = N;
        while (l < h2) { const int mid = (l + h2) >> 1; if (batch[mid] < g) l = mid + 1; else h2 = mid; }
        lo = l;
        h2 = N;
        while (l < h2) { const int mid = (l + h2) >> 1; if (batch[mid] < g + 1) l = mid + 1; else h2 = mid; }
        hi = l;
    }
    __shared__ float part[16][128];
    __shared__ float pl[128];
    __shared__ float red2[32];
    const int tid = threadIdx.x;
    const int c8 = (tid & 15) * 8, r = tid >> 4;
    float a8[8];
    #pragma unroll
    for (int j = 0; j < 8; ++j) a8[j] = 0.f;
    for (int n = lo + r; n < hi; n += 16) {
        const uint4 u = *reinterpret_cast<const uint4*>(&Ab[(size_t)n * 128 + c8]);
        a8[0] += B2F_LO(u.x); a8[1] += B2F_HI(u.x);
        a8[2] += B2F_LO(u.y); a8[3] += B2F_HI(u.y);
        a8[4] += B2F_LO(u.z); a8[5] += B2F_HI(u.z);
        a8[6] += B2F_LO(u.w); a8[7] += B2F_HI(u.w);
    }
    #pragma unroll
    for (int j = 0; j < 8; ++j) part[r][c8 + j] = a8[j];
    __syncthreads();
    if (tid < 128) {
        float s = 0.f;
        #pragma unroll
        for (int rr = 0; rr < 16; ++rr) s += part[rr][tid];
        pl[tid] = s / fmaxf((float)(hi - lo), 1.f);
    }
    __syncthreads();
    if (tid < 32) {
        float a = fc1b[tid];
        for (int k = 0; k < 128; ++k) a += pl[k] * fc1w[k * 32 + tid];
        a = fmaxf(a, 0.f);
        red2[tid] = a * fc2w[tid];
    }
    __syncthreads();
    if (tid == 0) {
        float sum = fc2b[0];
        for (int k = 0; k < 32; ++k) sum += red2[k];
        out[g] = sum;
    }
}

// ======================= launch =======================

extern "C" void kernel_launch(void* const* d_in, const int* in_sizes, int n_in,
                              void* d_out, int out_size, void* d_ws, size_t ws_size,
                              hipStream_t stream) {
    const float* x     = (const float*)d_in[0];
    const int*   ei    = (const int*)  d_in[1];
    const int*   batch = (const int*)  d_in[2];
    const float* W1 = (const float*)d_in[3],  *as1 = (const float*)d_in[4],
               *ad1 = (const float*)d_in[5],  *b1  = (const float*)d_in[6];
    const float* W2 = (const float*)d_in[7],  *as2 = (const float*)d_in[8],
               *ad2 = (const float*)d_in[9],  *b2  = (const float*)d_in[10];
    const float* W3 = (const float*)d_in[11], *as3 = (const float*)d_in[12],
               *ad3 = (const float*)d_in[13], *b3  = (const float*)d_in[14];
    const float* fc1w = (const float*)d_in[15], *fc1b = (const float*)d_in[16];
    const float* fc2w = (const float*)d_in[17], *fc2b = (const float*)d_in[18];

    const int N  = in_sizes[0] / 16;     // 50000
    const int NE = in_sizes[1] / 2;      // 800000
    const int NG = out_size;             // 256
    const int ET = NE + N;               // edges incl. self-loops
    const int KB = (N + 255) >> 8;       // buckets of 256 dsts

    // workspace layout (16B alignment maintained)
    float* ws = (float*)d_ws;
    size_t off = 0;
    unsigned short* Ab = (unsigned short*)(ws + off); off += (size_t)N * 64;   // layer out (bf16)
    unsigned short* Hb = (unsigned short*)(ws + off); off += (size_t)N * 64;   // bf16 h
    float* als  = ws + off; off += (size_t)N * GAT_H;
    float* ald  = ws + off; off += (size_t)N * GAT_H;
    float* Mh   = ws + off; off += 3 * GAT_H;
    int* rowptr = (int*)(ws + off); off += N + 1;
    int* esrc   = (int*)(ws + off); off += ET;
    unsigned* staging = (unsigned*)(ws + off); off += (size_t)KB * BCAP;
    int* bwoff  = (int*)(ws + off); off += KBMAX;
    unsigned short* Wt2 = (unsigned short*)(ws + off); off += 128 * 64 / 2;    // [128][64] bf16
    unsigned short* Wt3 = (unsigned short*)(ws + off); off += 128 * 128 / 2;   // [128][128] bf16

    // ---- bucketed CSR build + W transposes ----
    hipMemsetAsync(bwoff, 0, KBMAX * sizeof(int), stream);
    bkt_scatter<<<(ET + 2047) / 2048, 256, 0, stream>>>(ei, bwoff, staging, Mh, NE, N, KB);
    bkt_build<<<KB, 1024, 0, stream>>>(staging, bwoff, rowptr, esrc, N, KB);
    wconv_kernel<<<(128 * 64 + 255) / 256, 256, 0, stream>>>(W2, Wt2, 64);
    wconv_kernel<<<(128 * 128 + 255) / 256, 256, 0, stream>>>(W3, Wt3, 128);

    const int NH = N * GAT_H;
    const int NHB = (NH + 255) / 256;
    const int NB = (N + 63) / 64;

    // ---- layer 1: 16 -> 8x8 (fp32 in, VALU fused) ----
    matmul_fused<16, 64, 16, 8><<<NB, 256, 0, stream>>>(x, W1, as1, ad1, Hb, als, ald, Mh, N);
    gat_gather<8><<<NHB, 256, 0, stream>>>(rowptr, esrc, als, ald, Mh, Hb, b1, Ab, N);

    // ---- layer 2: 64 -> 8x16 (MFMA, fused logits) ----
    matmul_mfma<64><<<NB, 256, 0, stream>>>(Ab, Wt2, as2, ad2, Hb, als, ald, Mh + GAT_H, N);
    gat_gather<16><<<NHB, 256, 0, stream>>>(rowptr, esrc, als, ald, Mh + GAT_H, Hb, b2, Ab, N);

    // ---- layer 3: 128 -> 8x16 (MFMA, fused logits) ----
    matmul_mfma<128><<<NB, 256, 0, stream>>>(Ab, Wt3, as3, ad3, Hb, als, ald, Mh + 2 * GAT_H, N);
    gat_gather<16><<<NHB, 256, 0, stream>>>(rowptr, esrc, als, ald, Mh + 2 * GAT_H, Hb, b3, Ab, N);

    // ---- pool + MLP ----
    pool_mlp_kernel<<<NG, 256, 0, stream>>>(Ab, batch, fc1w, fc1b, fc2w, fc2b,
                                            (float*)d_out, N);
}